// Round 7
// baseline (689.299 us; speedup 1.0000x reference)
//
#include <hip/hip_runtime.h>
#include <hip/hip_bf16.h>

#define IN_F 128
#define OUT_F 32
#define BSHIFT 6
#define NPB 64             // nodes per bucket (dst >> 6)
#define CHUNK 8192         // edges per chunk
#define BIN_THREADS 512
#define AGG_THREADS 256
#define ACC_STRIDE 33      // bank = (dL + c) & 31 -> conflict-free per edge
#define MAXB 2048
#define TILE_RECS 512      // recs staged in LDS per tile

static __device__ inline unsigned short f2bf_rne(float f) {
    unsigned u = __float_as_uint(f);
    unsigned r = u + 0x7FFF + ((u >> 16) & 1);   // round-to-nearest-even
    return (unsigned short)(r >> 16);
}

// ---------------- K1: h = x @ W, output bf16 (W staged in LDS) ----------------
__global__ void gcn_gemm_h(const float* __restrict__ x, const float* __restrict__ W,
                           unsigned short* __restrict__ h, int n_rows)
{
    __shared__ float Wl[IN_F * OUT_F];           // 16 KB
    const int tid = threadIdx.x;
    const float4* W4 = (const float4*)W;
    float4* Wl4 = (float4*)Wl;
    #pragma unroll
    for (int i = 0; i < 4; ++i)
        Wl4[tid + i * 256] = W4[tid + i * 256];
    __syncthreads();

    const int c4   = tid & 7;
    const int rloc = tid >> 3;
    const int row  = blockIdx.x * 32 + rloc;
    if (row >= n_rows) return;

    const float4* xr = (const float4*)(x + (size_t)row * IN_F);
    float4 acc = {0.f, 0.f, 0.f, 0.f};
    #pragma unroll
    for (int k4 = 0; k4 < IN_F / 4; ++k4) {
        const float4 xv = xr[k4];
        #pragma unroll
        for (int j = 0; j < 4; ++j) {
            const int k = k4 * 4 + j;
            const float4 wv = *(const float4*)(&Wl[k * OUT_F + c4 * 4]);
            const float xs = (&xv.x)[j];
            acc.x += xs * wv.x;
            acc.y += xs * wv.y;
            acc.z += xs * wv.z;
            acc.w += xs * wv.w;
        }
    }
    ushort4 o = { f2bf_rne(acc.x), f2bf_rne(acc.y), f2bf_rne(acc.z), f2bf_rne(acc.w) };
    *(ushort4*)(&h[(size_t)row * OUT_F + c4 * 4]) = o;
}

// ---------------- K2a: per-chunk histogram over buckets ----------------
__global__ __launch_bounds__(BIN_THREADS)
void gcn_count(const int* __restrict__ edst, int* __restrict__ cntT,
               int n_edges, int nb, int n_chunks)
{
    __shared__ int hist[MAXB];
    const int tid = threadIdx.x;
    const int k   = blockIdx.x;
    const int base  = k * CHUNK;
    const int count = min(CHUNK, n_edges - base);
    for (int i = tid; i < nb; i += BIN_THREADS) hist[i] = 0;
    __syncthreads();
    for (int i = tid; i < count; i += BIN_THREADS)
        atomicAdd(&hist[edst[base + i] >> BSHIFT], 1);
    __syncthreads();
    for (int i = tid; i < nb; i += BIN_THREADS)
        cntT[(size_t)i * n_chunks + k] = hist[i];      // [bucket][chunk]
}

// ---------------- K2b: per-bucket exclusive scan over chunks ----------------
__global__ __launch_bounds__(512)
void gcn_scan_bucket(const int* __restrict__ cntT, int* __restrict__ offT,
                     int* __restrict__ totals, int n_chunks, int nb)
{
    __shared__ int sh[512];
    const int b = blockIdx.x, tid = threadIdx.x;
    const int v = (tid < n_chunks) ? cntT[(size_t)b * n_chunks + tid] : 0;
    sh[tid] = v;
    __syncthreads();
    for (int off = 1; off < 512; off <<= 1) {
        int t = (tid >= off) ? sh[tid - off] : 0;
        __syncthreads();
        sh[tid] += t;
        __syncthreads();
    }
    if (tid < n_chunks) offT[(size_t)tid * nb + b] = sh[tid] - v;   // [chunk][bucket]
    if (tid == 511) totals[b] = sh[511];
}

// ---------------- K2c: exclusive scan of ROUNDED bucket totals ----------------
__global__ __launch_bounds__(1024)
void gcn_scan_total(const int* __restrict__ totals, int* __restrict__ colStart, int nb)
{
    __shared__ int sh[1024];
    __shared__ int carry_s;
    const int tid = threadIdx.x;
    if (tid == 0) carry_s = 0;
    __syncthreads();
    for (int base = 0; base < nb; base += 1024) {
        const int idx = base + tid;
        const int v = (idx < nb) ? ((totals[idx] + 31) & ~31) : 0;
        sh[tid] = v;
        __syncthreads();
        for (int off = 1; off < 1024; off <<= 1) {
            int t = (tid >= off) ? sh[tid - off] : 0;
            __syncthreads();
            sh[tid] += t;
            __syncthreads();
        }
        const int carry = carry_s;
        if (idx < nb) colStart[idx] = carry + sh[tid] - v;
        __syncthreads();
        if (tid == 1023) carry_s = carry + sh[1023];
        __syncthreads();
    }
    if (tid == 0) colStart[nb] = carry_s;
}

// ---------------- K2c2: zero only the pad slots ----------------
__global__ __launch_bounds__(64)
void gcn_padzero(const int* __restrict__ colStart, const int* __restrict__ totals,
                 int2* __restrict__ recs)
{
    const int b = blockIdx.x;
    const int start = colStart[b] + totals[b];
    const int end   = colStart[b + 1];
    const int t = threadIdx.x;
    if (start + t < end) recs[start + t] = make_int2(0, 0);
}

// ---------------- K2d: write records to final bucket-major slots ----------------
// Record: {src | (dstLocal<<17), w_bits}  (src < 2^17, dstLocal < 2^6)
__global__ __launch_bounds__(BIN_THREADS)
void gcn_bin(const int* __restrict__ esrc, const int* __restrict__ edst,
             const float* __restrict__ ew,
             const int* __restrict__ colStart, const int* __restrict__ offT,
             int2* __restrict__ recs, int n_edges, int nb, int n_chunks)
{
    __shared__ int cursor[MAXB];
    const int tid = threadIdx.x;
    const int k   = blockIdx.x;
    const int* offRow = offT + (size_t)k * nb;
    for (int i = tid; i < nb; i += BIN_THREADS)
        cursor[i] = colStart[i] + offRow[i];
    __syncthreads();

    const int base  = k * CHUNK;
    const int count = min(CHUNK, n_edges - base);
    for (int i = tid; i < count; i += BIN_THREADS) {
        const int e = base + i;
        const int d = edst[e];
        const int pos = atomicAdd(&cursor[d >> BSHIFT], 1);
        recs[pos] = make_int2(esrc[e] | ((d & (NPB - 1)) << 17), __float_as_int(ew[e]));
    }
}

// ---------------- K3: one block per bucket; 4 lanes own one edge ----------------
// recs staged in LDS (coalesced); each lane loads uint4 = 8 channels of its
// edge's h-row -> one wave vmem inst covers 16 edges x 64B = 1KB coalesced.
// 2x unrolled: two independent uint4 loads in flight per iteration.
__global__ __launch_bounds__(AGG_THREADS)
void gcn_aggregate(const unsigned short* __restrict__ h,
                   const int2* __restrict__ recs,
                   const int* __restrict__ colStart,
                   float* __restrict__ out, int n_nodes)
{
    __shared__ float acc[NPB * ACC_STRIDE];      // 8.4 KB
    __shared__ int2 rbuf[TILE_RECS];             // 4 KB
    const int b   = blockIdx.x;
    const int tid = threadIdx.x;

    for (int i = tid; i < NPB * ACC_STRIDE; i += AGG_THREADS) acc[i] = 0.f;

    const int s    = colStart[b];
    const int cnt  = colStart[b + 1] - s;        // multiple of 32 (padded)
    const int wave = tid >> 6;                   // 0..3
    const int lane = tid & 63;
    const int rsub = lane >> 2;                  // 0..15: rec within group of 16
    const int q    = lane & 3;                   // quarter of h-row (8 channels)

    for (int t0 = 0; t0 < cnt; t0 += TILE_RECS) {
        const int tcnt = min(TILE_RECS, cnt - t0);
        __syncthreads();                         // rbuf reuse (also covers acc init)
        for (int i = tid; i < tcnt; i += AGG_THREADS)
            rbuf[i] = recs[s + t0 + i];
        __syncthreads();

        const int wbeg = wave * (TILE_RECS / 4);
        const int wend = min(wbeg + TILE_RECS / 4, tcnt);
        // (wend - wbeg) is a multiple of 32 by construction
        for (int i = wbeg; i + 32 <= wend; i += 32) {
            const int2 ra = rbuf[i + rsub];
            const int2 rb = rbuf[i + 16 + rsub];
            const int  srcA = ra.x & 0x1FFFF;
            const int  srcB = rb.x & 0x1FFFF;
            const uint4 ha = *(const uint4*)(h + ((size_t)srcA << 5) + (q << 3));
            const uint4 hb = *(const uint4*)(h + ((size_t)srcB << 5) + (q << 3));

            const float wa = __int_as_float(ra.y);
            float* apA = acc + ((ra.x >> 17) & (NPB - 1)) * ACC_STRIDE + (q << 3);
            atomicAdd(apA + 0, wa * __uint_as_float(ha.x << 16));
            atomicAdd(apA + 1, wa * __uint_as_float(ha.x & 0xFFFF0000u));
            atomicAdd(apA + 2, wa * __uint_as_float(ha.y << 16));
            atomicAdd(apA + 3, wa * __uint_as_float(ha.y & 0xFFFF0000u));
            atomicAdd(apA + 4, wa * __uint_as_float(ha.z << 16));
            atomicAdd(apA + 5, wa * __uint_as_float(ha.z & 0xFFFF0000u));
            atomicAdd(apA + 6, wa * __uint_as_float(ha.w << 16));
            atomicAdd(apA + 7, wa * __uint_as_float(ha.w & 0xFFFF0000u));

            const float wb = __int_as_float(rb.y);
            float* apB = acc + ((rb.x >> 17) & (NPB - 1)) * ACC_STRIDE + (q << 3);
            atomicAdd(apB + 0, wb * __uint_as_float(hb.x << 16));
            atomicAdd(apB + 1, wb * __uint_as_float(hb.x & 0xFFFF0000u));
            atomicAdd(apB + 2, wb * __uint_as_float(hb.y << 16));
            atomicAdd(apB + 3, wb * __uint_as_float(hb.y & 0xFFFF0000u));
            atomicAdd(apB + 4, wb * __uint_as_float(hb.z << 16));
            atomicAdd(apB + 5, wb * __uint_as_float(hb.z & 0xFFFF0000u));
            atomicAdd(apB + 6, wb * __uint_as_float(hb.w << 16));
            atomicAdd(apB + 7, wb * __uint_as_float(hb.w & 0xFFFF0000u));
        }
    }
    __syncthreads();

    const int nodeBase = b << BSHIFT;
    const int nvalid   = min(NPB, n_nodes - nodeBase);
    for (int i = tid; i < (nvalid * OUT_F) / 4; i += AGG_THREADS) {
        const int node = (i * 4) >> 5;
        const int cc   = (i * 4) & 31;
        const float* ap = acc + node * ACC_STRIDE + cc;
        float4 v = { ap[0], ap[1], ap[2], ap[3] };
        *(float4*)(out + ((size_t)(nodeBase + node) << 5) + cc) = v;
    }
}

// ---------------- Fallback (no/small ws): fused, atomics into out ----------------
__global__ void gcn_fused_fallback(const float* __restrict__ x, const float* __restrict__ W,
                                   const int* __restrict__ esrc,
                                   const int* __restrict__ edst,
                                   const float* __restrict__ ew,
                                   float* __restrict__ out,
                                   long long total_units)
{
    __shared__ float Wl[IN_F * OUT_F];
    const int tid = threadIdx.x;
    const float4* W4 = (const float4*)W;
    float4* Wl4 = (float4*)Wl;
    #pragma unroll
    for (int i = 0; i < 4; ++i)
        Wl4[tid + i * 256] = W4[tid + i * 256];
    __syncthreads();

    long long u = (long long)blockIdx.x * blockDim.x + threadIdx.x;
    if (u >= total_units) return;
    const int e = (int)(u >> 5);
    const int c = (int)(u & 31);
    const int s  = esrc[e];
    const int d  = edst[e];
    const float w = ew[e];

    const float4* xr = (const float4*)(x + (size_t)s * IN_F);
    float acc = 0.f;
    #pragma unroll
    for (int k4 = 0; k4 < IN_F / 4; ++k4) {
        const float4 xv = xr[k4];
        acc += xv.x * Wl[(k4 * 4 + 0) * OUT_F + c];
        acc += xv.y * Wl[(k4 * 4 + 1) * OUT_F + c];
        acc += xv.z * Wl[(k4 * 4 + 2) * OUT_F + c];
        acc += xv.w * Wl[(k4 * 4 + 3) * OUT_F + c];
    }
    atomicAdd(out + (size_t)d * OUT_F + c, w * acc);
}

static inline size_t align_up(size_t v, size_t a) { return (v + a - 1) & ~(a - 1); }

extern "C" void kernel_launch(void* const* d_in, const int* in_sizes, int n_in,
                              void* d_out, int out_size, void* d_ws, size_t ws_size,
                              hipStream_t stream)
{
    const float* x  = (const float*)d_in[0];
    const float* W  = (const float*)d_in[1];
    const int* esrc = (const int*)d_in[2];
    const int* edst = (const int*)d_in[3];
    const float* ew = (const float*)d_in[4];
    float* out = (float*)d_out;

    const int n_nodes = in_sizes[0] / IN_F;
    const int n_edges = in_sizes[2];

    const int nb       = (n_nodes + NPB - 1) >> BSHIFT;    // 1563
    const int n_chunks = (n_edges + CHUNK - 1) / CHUNK;    // 391

    const size_t h_bytes    = align_up((size_t)n_nodes * OUT_F * sizeof(unsigned short), 256);
    const size_t cnt_bytes  = align_up((size_t)nb * n_chunks * sizeof(int), 256);
    const size_t off_bytes  = align_up((size_t)nb * n_chunks * sizeof(int), 256);
    const size_t tot_bytes  = align_up((size_t)nb * sizeof(int), 256);
    const size_t col_bytes  = align_up(((size_t)nb + 1) * sizeof(int), 256);
    const size_t recs_bytes = align_up(((size_t)n_edges + 32 * (size_t)nb) * sizeof(int2), 256);
    const size_t need = h_bytes + cnt_bytes + off_bytes + tot_bytes + col_bytes + recs_bytes;

    if (ws_size >= need && nb <= MAXB && n_chunks <= 512) {
        char* p = (char*)d_ws;
        unsigned short* h = (unsigned short*)p;  p += h_bytes;
        int* cntT     = (int*)p;                 p += cnt_bytes;
        int* offT     = (int*)p;                 p += off_bytes;
        int* totals   = (int*)p;                 p += tot_bytes;
        int* colStart = (int*)p;                 p += col_bytes;
        int2* recs    = (int2*)p;

        const int gemm_blocks = (n_nodes + 31) / 32;
        gcn_gemm_h<<<gemm_blocks, 256, 0, stream>>>(x, W, h, n_nodes);

        gcn_count<<<n_chunks, BIN_THREADS, 0, stream>>>(edst, cntT, n_edges, nb, n_chunks);
        gcn_scan_bucket<<<nb, 512, 0, stream>>>(cntT, offT, totals, n_chunks, nb);
        gcn_scan_total<<<1, 1024, 0, stream>>>(totals, colStart, nb);
        gcn_padzero<<<nb, 64, 0, stream>>>(colStart, totals, recs);
        gcn_bin<<<n_chunks, BIN_THREADS, 0, stream>>>(esrc, edst, ew, colStart, offT,
                                                      recs, n_edges, nb, n_chunks);
        gcn_aggregate<<<nb, AGG_THREADS, 0, stream>>>(h, recs, colStart, out, n_nodes);
    } else {
        hipMemsetAsync(d_out, 0, (size_t)out_size * sizeof(float), stream);
        const long long total_units = (long long)n_edges * 32;
        const int fblocks = (int)((total_units + 255) / 256);
        gcn_fused_fallback<<<fblocks, 256, 0, stream>>>(x, W, esrc, edst, ew, out, total_units);
    }
}

// Round 8
// 170.236 us; speedup vs baseline: 4.0491x; 4.0491x over previous
//
#include <hip/hip_runtime.h>
#include <hip/hip_bf16.h>

#define IN_F 128
#define OUT_F 32
#define BSHIFT 6
#define NPB 64             // nodes per bucket (dst >> 6)
#define CHUNK 8192         // edges per chunk
#define BIN_THREADS 512
#define SORT_THREADS 256
#define SORT_CAP 4096      // max recs sorted in LDS per bucket (mean 2048, sigma 45)
#define MAXB 2048

static __device__ inline unsigned short f2bf_rne(float f) {
    unsigned u = __float_as_uint(f);
    unsigned r = u + 0x7FFF + ((u >> 16) & 1);   // round-to-nearest-even
    return (unsigned short)(r >> 16);
}

// ---------------- K1: h = x @ W, output bf16 (W staged in LDS) ----------------
__global__ void gcn_gemm_h(const float* __restrict__ x, const float* __restrict__ W,
                           unsigned short* __restrict__ h, int n_rows)
{
    __shared__ float Wl[IN_F * OUT_F];           // 16 KB
    const int tid = threadIdx.x;
    const float4* W4 = (const float4*)W;
    float4* Wl4 = (float4*)Wl;
    #pragma unroll
    for (int i = 0; i < 4; ++i)
        Wl4[tid + i * 256] = W4[tid + i * 256];
    __syncthreads();

    const int c4   = tid & 7;
    const int rloc = tid >> 3;
    const int row  = blockIdx.x * 32 + rloc;
    if (row >= n_rows) return;

    const float4* xr = (const float4*)(x + (size_t)row * IN_F);
    float4 acc = {0.f, 0.f, 0.f, 0.f};
    #pragma unroll
    for (int k4 = 0; k4 < IN_F / 4; ++k4) {
        const float4 xv = xr[k4];
        #pragma unroll
        for (int j = 0; j < 4; ++j) {
            const int k = k4 * 4 + j;
            const float4 wv = *(const float4*)(&Wl[k * OUT_F + c4 * 4]);
            const float xs = (&xv.x)[j];
            acc.x += xs * wv.x;
            acc.y += xs * wv.y;
            acc.z += xs * wv.z;
            acc.w += xs * wv.w;
        }
    }
    ushort4 o = { f2bf_rne(acc.x), f2bf_rne(acc.y), f2bf_rne(acc.z), f2bf_rne(acc.w) };
    *(ushort4*)(&h[(size_t)row * OUT_F + c4 * 4]) = o;
}

// ---------------- K2a: per-chunk histogram over buckets ----------------
__global__ __launch_bounds__(BIN_THREADS)
void gcn_count(const int* __restrict__ edst, int* __restrict__ cntT,
               int n_edges, int nb, int n_chunks)
{
    __shared__ int hist[MAXB];
    const int tid = threadIdx.x;
    const int k   = blockIdx.x;
    const int base  = k * CHUNK;
    const int count = min(CHUNK, n_edges - base);
    for (int i = tid; i < nb; i += BIN_THREADS) hist[i] = 0;
    __syncthreads();
    for (int i = tid; i < count; i += BIN_THREADS)
        atomicAdd(&hist[edst[base + i] >> BSHIFT], 1);
    __syncthreads();
    for (int i = tid; i < nb; i += BIN_THREADS)
        cntT[(size_t)i * n_chunks + k] = hist[i];      // [bucket][chunk]
}

// ---------------- K2b: per-bucket exclusive scan over chunks ----------------
__global__ __launch_bounds__(512)
void gcn_scan_bucket(const int* __restrict__ cntT, int* __restrict__ offT,
                     int* __restrict__ totals, int n_chunks, int nb)
{
    __shared__ int sh[512];
    const int b = blockIdx.x, tid = threadIdx.x;
    const int v = (tid < n_chunks) ? cntT[(size_t)b * n_chunks + tid] : 0;
    sh[tid] = v;
    __syncthreads();
    for (int off = 1; off < 512; off <<= 1) {
        int t = (tid >= off) ? sh[tid - off] : 0;
        __syncthreads();
        sh[tid] += t;
        __syncthreads();
    }
    if (tid < n_chunks) offT[(size_t)tid * nb + b] = sh[tid] - v;   // [chunk][bucket]
    if (tid == 511) totals[b] = sh[511];
}

// ---------------- K2c: exclusive scan of bucket totals (no padding) ----------------
__global__ __launch_bounds__(1024)
void gcn_scan_total(const int* __restrict__ totals, int* __restrict__ colStart, int nb)
{
    __shared__ int sh[1024];
    __shared__ int carry_s;
    const int tid = threadIdx.x;
    if (tid == 0) carry_s = 0;
    __syncthreads();
    for (int base = 0; base < nb; base += 1024) {
        const int idx = base + tid;
        const int v = (idx < nb) ? totals[idx] : 0;
        sh[tid] = v;
        __syncthreads();
        for (int off = 1; off < 1024; off <<= 1) {
            int t = (tid >= off) ? sh[tid - off] : 0;
            __syncthreads();
            sh[tid] += t;
            __syncthreads();
        }
        const int carry = carry_s;
        if (idx < nb) colStart[idx] = carry + sh[tid] - v;
        __syncthreads();
        if (tid == 1023) carry_s = carry + sh[1023];
        __syncthreads();
    }
    if (tid == 0) colStart[nb] = carry_s;
}

// ---------------- K2d: write records to bucket-major slots ----------------
// Record: {src | (dstLocal<<17), w_bits}  (src < 2^17, dstLocal < 2^6)
__global__ __launch_bounds__(BIN_THREADS)
void gcn_bin(const int* __restrict__ esrc, const int* __restrict__ edst,
             const float* __restrict__ ew,
             const int* __restrict__ colStart, const int* __restrict__ offT,
             int2* __restrict__ recs, int n_edges, int nb, int n_chunks)
{
    __shared__ int cursor[MAXB];
    const int tid = threadIdx.x;
    const int k   = blockIdx.x;
    const int* offRow = offT + (size_t)k * nb;
    for (int i = tid; i < nb; i += BIN_THREADS)
        cursor[i] = colStart[i] + offRow[i];
    __syncthreads();

    const int base  = k * CHUNK;
    const int count = min(CHUNK, n_edges - base);
    for (int i = tid; i < count; i += BIN_THREADS) {
        const int e = base + i;
        const int d = edst[e];
        const int pos = atomicAdd(&cursor[d >> BSHIFT], 1);
        recs[pos] = make_int2(esrc[e] | ((d & (NPB - 1)) << 17), __float_as_int(ew[e]));
    }
}

// ---------------- K2e: per-bucket in-LDS counting sort by dstLocal ----------------
// Produces node-level CSR ranges [nodeBeg, nodeEnd) and node-sorted recs in place.
// Fallback (cnt > SORT_CAP): leave unsorted; node range = whole bucket (gather filters).
__global__ __launch_bounds__(SORT_THREADS)
void gcn_sort(int2* __restrict__ recs, const int* __restrict__ colStart,
              int* __restrict__ nodeBeg, int* __restrict__ nodeEnd, int n_nodes)
{
    __shared__ int2 sbuf[SORT_CAP];              // 32 KB
    __shared__ int hist[NPB];
    __shared__ int excl[NPB];
    __shared__ int cursor[NPB];
    const int b   = blockIdx.x;
    const int tid = threadIdx.x;
    const int s   = colStart[b];
    const int cnt = colStart[b + 1] - s;
    const int nodeBase = b << BSHIFT;

    if (cnt > SORT_CAP) {     // ultra-rare safety path: unsorted, full-range + filter
        if (tid < NPB && nodeBase + tid < n_nodes) {
            nodeBeg[nodeBase + tid] = s;
            nodeEnd[nodeBase + tid] = s + cnt;
        }
        return;
    }

    if (tid < NPB) hist[tid] = 0;
    __syncthreads();
    for (int i = tid; i < cnt; i += SORT_THREADS) {
        sbuf[i] = recs[s + i];
        atomicAdd(&hist[(sbuf[i].x >> 17) & (NPB - 1)], 1);
    }
    __syncthreads();
    if (tid < NPB) {          // wave-local exclusive scan over 64 entries
        int v = hist[tid];
        int sc = v;
        #pragma unroll
        for (int off = 1; off < NPB; off <<= 1) {
            int t = __shfl_up(sc, off, 64);
            if ((tid & 63) >= off) sc += t;
        }
        excl[tid]   = sc - v;
        cursor[tid] = sc - v;
        if (nodeBase + tid < n_nodes) {
            nodeBeg[nodeBase + tid] = s + sc - v;
            nodeEnd[nodeBase + tid] = s + sc;
        }
    }
    __syncthreads();
    for (int i = tid; i < cnt; i += SORT_THREADS) {
        const int2 r = sbuf[i];
        const int pos = atomicAdd(&cursor[(r.x >> 17) & (NPB - 1)], 1);
        recs[s + pos] = r;    // scattered within dense 16KB region -> L2 absorbs
    }
}

// ---------------- K3: gather — half-wave per node, register acc, NO atomics ----------------
__global__ __launch_bounds__(256)
void gcn_gather(const unsigned short* __restrict__ h,
                const int2* __restrict__ recs,
                const int* __restrict__ nodeBeg, const int* __restrict__ nodeEnd,
                float* __restrict__ out, int n_nodes)
{
    const int node = blockIdx.x * 8 + (threadIdx.x >> 5);
    const int c    = threadIdx.x & 31;
    if (node >= n_nodes) return;

    const int myDL = node & (NPB - 1);
    int i   = nodeBeg[node];
    const int e = nodeEnd[node];
    float acc = 0.f;

    // align to even index for int4 (16B) rec loads
    if ((i & 1) && i < e) {
        const int2 r = recs[i];
        const unsigned hv = h[((size_t)(r.x & 0x1FFFF) << 5) + c];
        const float v = __int_as_float(r.y) * __uint_as_float(hv << 16);
        acc += (((r.x >> 17) & (NPB - 1)) == myDL) ? v : 0.f;
        ++i;
    }
    for (; i + 4 <= e; i += 4) {
        const int4 ra = *(const int4*)(recs + i);        // recs[i], recs[i+1]
        const int4 rb = *(const int4*)(recs + i + 2);    // recs[i+2], recs[i+3]
        const unsigned h0 = h[((size_t)(ra.x & 0x1FFFF) << 5) + c];
        const unsigned h1 = h[((size_t)(ra.z & 0x1FFFF) << 5) + c];
        const unsigned h2 = h[((size_t)(rb.x & 0x1FFFF) << 5) + c];
        const unsigned h3 = h[((size_t)(rb.z & 0x1FFFF) << 5) + c];
        const float v0 = __int_as_float(ra.y) * __uint_as_float(h0 << 16);
        const float v1 = __int_as_float(ra.w) * __uint_as_float(h1 << 16);
        const float v2 = __int_as_float(rb.y) * __uint_as_float(h2 << 16);
        const float v3 = __int_as_float(rb.w) * __uint_as_float(h3 << 16);
        acc += (((ra.x >> 17) & (NPB - 1)) == myDL) ? v0 : 0.f;
        acc += (((ra.z >> 17) & (NPB - 1)) == myDL) ? v1 : 0.f;
        acc += (((rb.x >> 17) & (NPB - 1)) == myDL) ? v2 : 0.f;
        acc += (((rb.z >> 17) & (NPB - 1)) == myDL) ? v3 : 0.f;
    }
    for (; i < e; ++i) {
        const int2 r = recs[i];
        const unsigned hv = h[((size_t)(r.x & 0x1FFFF) << 5) + c];
        const float v = __int_as_float(r.y) * __uint_as_float(hv << 16);
        acc += (((r.x >> 17) & (NPB - 1)) == myDL) ? v : 0.f;
    }
    out[((size_t)node << 5) + c] = acc;
}

// ---------------- Fallback (no/small ws): fused, atomics into out ----------------
__global__ void gcn_fused_fallback(const float* __restrict__ x, const float* __restrict__ W,
                                   const int* __restrict__ esrc,
                                   const int* __restrict__ edst,
                                   const float* __restrict__ ew,
                                   float* __restrict__ out,
                                   long long total_units)
{
    __shared__ float Wl[IN_F * OUT_F];
    const int tid = threadIdx.x;
    const float4* W4 = (const float4*)W;
    float4* Wl4 = (float4*)Wl;
    #pragma unroll
    for (int i = 0; i < 4; ++i)
        Wl4[tid + i * 256] = W4[tid + i * 256];
    __syncthreads();

    long long u = (long long)blockIdx.x * blockDim.x + threadIdx.x;
    if (u >= total_units) return;
    const int e = (int)(u >> 5);
    const int c = (int)(u & 31);
    const int s  = esrc[e];
    const int d  = edst[e];
    const float w = ew[e];

    const float4* xr = (const float4*)(x + (size_t)s * IN_F);
    float acc = 0.f;
    #pragma unroll
    for (int k4 = 0; k4 < IN_F / 4; ++k4) {
        const float4 xv = xr[k4];
        acc += xv.x * Wl[(k4 * 4 + 0) * OUT_F + c];
        acc += xv.y * Wl[(k4 * 4 + 1) * OUT_F + c];
        acc += xv.z * Wl[(k4 * 4 + 2) * OUT_F + c];
        acc += xv.w * Wl[(k4 * 4 + 3) * OUT_F + c];
    }
    atomicAdd(out + (size_t)d * OUT_F + c, w * acc);
}

static inline size_t align_up(size_t v, size_t a) { return (v + a - 1) & ~(a - 1); }

extern "C" void kernel_launch(void* const* d_in, const int* in_sizes, int n_in,
                              void* d_out, int out_size, void* d_ws, size_t ws_size,
                              hipStream_t stream)
{
    const float* x  = (const float*)d_in[0];
    const float* W  = (const float*)d_in[1];
    const int* esrc = (const int*)d_in[2];
    const int* edst = (const int*)d_in[3];
    const float* ew = (const float*)d_in[4];
    float* out = (float*)d_out;

    const int n_nodes = in_sizes[0] / IN_F;
    const int n_edges = in_sizes[2];

    const int nb       = (n_nodes + NPB - 1) >> BSHIFT;    // 1563
    const int n_chunks = (n_edges + CHUNK - 1) / CHUNK;    // 391

    const size_t h_bytes    = align_up((size_t)n_nodes * OUT_F * sizeof(unsigned short), 256);
    const size_t cnt_bytes  = align_up((size_t)nb * n_chunks * sizeof(int), 256);
    const size_t off_bytes  = align_up((size_t)nb * n_chunks * sizeof(int), 256);
    const size_t tot_bytes  = align_up((size_t)nb * sizeof(int), 256);
    const size_t col_bytes  = align_up(((size_t)nb + 1) * sizeof(int), 256);
    const size_t nbg_bytes  = align_up((size_t)n_nodes * sizeof(int), 256);
    const size_t nen_bytes  = align_up((size_t)n_nodes * sizeof(int), 256);
    const size_t recs_bytes = align_up((size_t)n_edges * sizeof(int2) + 16, 256);
    const size_t need = h_bytes + cnt_bytes + off_bytes + tot_bytes + col_bytes
                      + nbg_bytes + nen_bytes + recs_bytes;

    if (ws_size >= need && nb <= MAXB && n_chunks <= 512) {
        char* p = (char*)d_ws;
        unsigned short* h = (unsigned short*)p;  p += h_bytes;
        int* cntT     = (int*)p;                 p += cnt_bytes;
        int* offT     = (int*)p;                 p += off_bytes;
        int* totals   = (int*)p;                 p += tot_bytes;
        int* colStart = (int*)p;                 p += col_bytes;
        int* nodeBg   = (int*)p;                 p += nbg_bytes;
        int* nodeEn   = (int*)p;                 p += nen_bytes;
        int2* recs    = (int2*)p;

        const int gemm_blocks = (n_nodes + 31) / 32;
        gcn_gemm_h<<<gemm_blocks, 256, 0, stream>>>(x, W, h, n_nodes);

        gcn_count<<<n_chunks, BIN_THREADS, 0, stream>>>(edst, cntT, n_edges, nb, n_chunks);
        gcn_scan_bucket<<<nb, 512, 0, stream>>>(cntT, offT, totals, n_chunks, nb);
        gcn_scan_total<<<1, 1024, 0, stream>>>(totals, colStart, nb);
        gcn_bin<<<n_chunks, BIN_THREADS, 0, stream>>>(esrc, edst, ew, colStart, offT,
                                                      recs, n_edges, nb, n_chunks);
        gcn_sort<<<nb, SORT_THREADS, 0, stream>>>(recs, colStart, nodeBg, nodeEn, n_nodes);
        gcn_gather<<<(n_nodes + 7) / 8, 256, 0, stream>>>(h, recs, nodeBg, nodeEn,
                                                          out, n_nodes);
    } else {
        hipMemsetAsync(d_out, 0, (size_t)out_size * sizeof(float), stream);
        const long long total_units = (long long)n_edges * 32;
        const int fblocks = (int)((total_units + 255) / 256);
        gcn_fused_fallback<<<fblocks, 256, 0, stream>>>(x, W, esrc, edst, ew, out, total_units);
    }
}

// Round 9
// 127.301 us; speedup vs baseline: 5.4147x; 1.3373x over previous
//
#include <hip/hip_runtime.h>
#include <hip/hip_bf16.h>

#define IN_F 128
#define OUT_F 32
#define BSHIFT 8
#define NPB 256            // nodes per bucket (dst >> 8)
#define CHUNK 8192         // edges per chunk
#define BIN_THREADS 512
#define GAT_THREADS 1024
#define TILE 4096          // recs per LDS tile in fused sort+gather
#define MAXB 512

static __device__ inline unsigned short f2bf_rne(float f) {
    unsigned u = __float_as_uint(f);
    unsigned r = u + 0x7FFF + ((u >> 16) & 1);   // round-to-nearest-even
    return (unsigned short)(r >> 16);
}

// ---------------- K1: h = x @ W, output bf16 (W staged in LDS) ----------------
__global__ void gcn_gemm_h(const float* __restrict__ x, const float* __restrict__ W,
                           unsigned short* __restrict__ h, int n_rows)
{
    __shared__ float Wl[IN_F * OUT_F];           // 16 KB
    const int tid = threadIdx.x;
    const float4* W4 = (const float4*)W;
    float4* Wl4 = (float4*)Wl;
    #pragma unroll
    for (int i = 0; i < 4; ++i)
        Wl4[tid + i * 256] = W4[tid + i * 256];
    __syncthreads();

    const int c4   = tid & 7;
    const int rloc = tid >> 3;
    const int row  = blockIdx.x * 32 + rloc;
    if (row >= n_rows) return;

    const float4* xr = (const float4*)(x + (size_t)row * IN_F);
    float4 acc = {0.f, 0.f, 0.f, 0.f};
    #pragma unroll
    for (int k4 = 0; k4 < IN_F / 4; ++k4) {
        const float4 xv = xr[k4];
        #pragma unroll
        for (int j = 0; j < 4; ++j) {
            const int k = k4 * 4 + j;
            const float4 wv = *(const float4*)(&Wl[k * OUT_F + c4 * 4]);
            const float xs = (&xv.x)[j];
            acc.x += xs * wv.x;
            acc.y += xs * wv.y;
            acc.z += xs * wv.z;
            acc.w += xs * wv.w;
        }
    }
    ushort4 o = { f2bf_rne(acc.x), f2bf_rne(acc.y), f2bf_rne(acc.z), f2bf_rne(acc.w) };
    *(ushort4*)(&h[(size_t)row * OUT_F + c4 * 4]) = o;
}

// ---------------- K2a: per-chunk histogram over buckets ----------------
__global__ __launch_bounds__(BIN_THREADS)
void gcn_count(const int* __restrict__ edst, int* __restrict__ cntT,
               int n_edges, int nb, int n_chunks)
{
    __shared__ int hist[MAXB];
    const int tid = threadIdx.x;
    const int k   = blockIdx.x;
    const int base  = k * CHUNK;
    const int count = min(CHUNK, n_edges - base);
    for (int i = tid; i < nb; i += BIN_THREADS) hist[i] = 0;
    __syncthreads();
    for (int i = tid; i < count; i += BIN_THREADS)
        atomicAdd(&hist[edst[base + i] >> BSHIFT], 1);
    __syncthreads();
    for (int i = tid; i < nb; i += BIN_THREADS)
        cntT[(size_t)i * n_chunks + k] = hist[i];      // [bucket][chunk]
}

// ---------------- K2b: per-bucket exclusive scan over chunks ----------------
__global__ __launch_bounds__(512)
void gcn_scan_bucket(const int* __restrict__ cntT, int* __restrict__ offT,
                     int* __restrict__ totals, int n_chunks, int nb)
{
    __shared__ int sh[512];
    const int b = blockIdx.x, tid = threadIdx.x;
    const int v = (tid < n_chunks) ? cntT[(size_t)b * n_chunks + tid] : 0;
    sh[tid] = v;
    __syncthreads();
    for (int off = 1; off < 512; off <<= 1) {
        int t = (tid >= off) ? sh[tid - off] : 0;
        __syncthreads();
        sh[tid] += t;
        __syncthreads();
    }
    if (tid < n_chunks) offT[(size_t)tid * nb + b] = sh[tid] - v;   // [chunk][bucket]
    if (tid == 511) totals[b] = sh[511];
}

// ---------------- K2c: exclusive scan of bucket totals ----------------
__global__ __launch_bounds__(1024)
void gcn_scan_total(const int* __restrict__ totals, int* __restrict__ colStart, int nb)
{
    __shared__ int sh[1024];
    __shared__ int carry_s;
    const int tid = threadIdx.x;
    if (tid == 0) carry_s = 0;
    __syncthreads();
    for (int base = 0; base < nb; base += 1024) {
        const int idx = base + tid;
        const int v = (idx < nb) ? totals[idx] : 0;
        sh[tid] = v;
        __syncthreads();
        for (int off = 1; off < 1024; off <<= 1) {
            int t = (tid >= off) ? sh[tid - off] : 0;
            __syncthreads();
            sh[tid] += t;
            __syncthreads();
        }
        const int carry = carry_s;
        if (idx < nb) colStart[idx] = carry + sh[tid] - v;
        __syncthreads();
        if (tid == 1023) carry_s = carry + sh[1023];
        __syncthreads();
    }
    if (tid == 0) colStart[nb] = carry_s;
}

// ---------------- K2d: write records to bucket-major slots ----------------
// Record: {src | (dstLocal<<17), w_bits}  (src < 2^17, dstLocal < 2^8)
__global__ __launch_bounds__(BIN_THREADS)
void gcn_bin(const int* __restrict__ esrc, const int* __restrict__ edst,
             const float* __restrict__ ew,
             const int* __restrict__ colStart, const int* __restrict__ offT,
             int2* __restrict__ recs, int n_edges, int nb, int n_chunks)
{
    __shared__ int cursor[MAXB];
    const int tid = threadIdx.x;
    const int k   = blockIdx.x;
    const int* offRow = offT + (size_t)k * nb;
    for (int i = tid; i < nb; i += BIN_THREADS)
        cursor[i] = colStart[i] + offRow[i];
    __syncthreads();

    const int base  = k * CHUNK;
    const int count = min(CHUNK, n_edges - base);
    for (int i = tid; i < count; i += BIN_THREADS) {
        const int e = base + i;
        const int d = edst[e];
        const int pos = atomicAdd(&cursor[d >> BSHIFT], 1);
        recs[pos] = make_int2(esrc[e] | ((d & (NPB - 1)) << 17), __float_as_int(ew[e]));
    }
}

// ---------------- K3: fused per-bucket LDS sort + register gather ----------------
// One block per bucket. Tiles of TILE recs: stage->hist->scan->scatter(sorted)
// in LDS, then each half-wave (32 lanes = channels) gathers its 8 owned nodes
// with register accumulators persisting across tiles. No global sorted recs.
__global__ __launch_bounds__(GAT_THREADS)
void gcn_sort_gather(const unsigned short* __restrict__ h,
                     const int2* __restrict__ recs,
                     const int* __restrict__ colStart,
                     float* __restrict__ out, int n_nodes)
{
    __shared__ int2 sbuf[TILE];       // 32 KB
    __shared__ int2 sorted[TILE];     // 32 KB
    __shared__ int hist[NPB];
    __shared__ int nbeg[NPB];
    __shared__ int cursor[NPB];

    const int b   = blockIdx.x;
    const int tid = threadIdx.x;
    const int s   = colStart[b];
    const int cnt = colStart[b + 1] - s;
    const int hw  = tid >> 5;          // 0..31: half-wave id, owns nodes hw*8..hw*8+7
    const int c   = tid & 31;          // channel

    float acc[8] = {0.f, 0.f, 0.f, 0.f, 0.f, 0.f, 0.f, 0.f};

    for (int t0 = 0; t0 < cnt; t0 += TILE) {
        const int tc = min(TILE, cnt - t0);
        __syncthreads();               // previous tile's gather done before reuse
        for (int i = tid; i < NPB; i += GAT_THREADS) hist[i] = 0;
        __syncthreads();
        for (int i = tid; i < tc; i += GAT_THREADS) {
            const int2 r = recs[s + t0 + i];
            sbuf[i] = r;
            atomicAdd(&hist[(r.x >> 17) & (NPB - 1)], 1);
        }
        __syncthreads();
        // inclusive scan over NPB entries (Hillis-Steele in LDS)
        if (tid < NPB) nbeg[tid] = hist[tid];
        __syncthreads();
        #pragma unroll
        for (int off = 1; off < NPB; off <<= 1) {
            int t = 0;
            if (tid < NPB && tid >= off) t = nbeg[tid - off];
            __syncthreads();
            if (tid < NPB) nbeg[tid] += t;
            __syncthreads();
        }
        if (tid < NPB) {
            const int beg = nbeg[tid] - hist[tid];   // exclusive
            nbeg[tid]   = beg;
            cursor[tid] = beg;
        }
        __syncthreads();
        for (int i = tid; i < tc; i += GAT_THREADS) {
            const int2 r = sbuf[i];
            const int pos = atomicAdd(&cursor[(r.x >> 17) & (NPB - 1)], 1);
            sorted[pos] = r;
        }
        __syncthreads();

        // gather: 8 nodes per half-wave, register acc, LDS rec broadcast
        #pragma unroll
        for (int n = 0; n < 8; ++n) {
            const int dL = (hw << 3) + n;
            int i = nbeg[dL];
            const int e = i + hist[dL];
            float a = 0.f;
            for (; i + 4 <= e; i += 4) {
                const int2 r0 = sorted[i];
                const int2 r1 = sorted[i + 1];
                const int2 r2 = sorted[i + 2];
                const int2 r3 = sorted[i + 3];
                const unsigned h0 = h[((size_t)(r0.x & 0x1FFFF) << 5) + c];
                const unsigned h1 = h[((size_t)(r1.x & 0x1FFFF) << 5) + c];
                const unsigned h2 = h[((size_t)(r2.x & 0x1FFFF) << 5) + c];
                const unsigned h3 = h[((size_t)(r3.x & 0x1FFFF) << 5) + c];
                a += __int_as_float(r0.y) * __uint_as_float(h0 << 16)
                   + __int_as_float(r1.y) * __uint_as_float(h1 << 16)
                   + __int_as_float(r2.y) * __uint_as_float(h2 << 16)
                   + __int_as_float(r3.y) * __uint_as_float(h3 << 16);
            }
            for (; i < e; ++i) {
                const int2 r = sorted[i];
                const unsigned hv = h[((size_t)(r.x & 0x1FFFF) << 5) + c];
                a += __int_as_float(r.y) * __uint_as_float(hv << 16);
            }
            acc[n] += a;
        }
    }

    const int nodeBase = b << BSHIFT;
    #pragma unroll
    for (int n = 0; n < 8; ++n) {
        const int node = nodeBase + (hw << 3) + n;
        if (node < n_nodes)
            out[((size_t)node << 5) + c] = acc[n];
    }
}

// ---------------- Fallback (no/small ws): fused, atomics into out ----------------
__global__ void gcn_fused_fallback(const float* __restrict__ x, const float* __restrict__ W,
                                   const int* __restrict__ esrc,
                                   const int* __restrict__ edst,
                                   const float* __restrict__ ew,
                                   float* __restrict__ out,
                                   long long total_units)
{
    __shared__ float Wl[IN_F * OUT_F];
    const int tid = threadIdx.x;
    const float4* W4 = (const float4*)W;
    float4* Wl4 = (float4*)Wl;
    #pragma unroll
    for (int i = 0; i < 4; ++i)
        Wl4[tid + i * 256] = W4[tid + i * 256];
    __syncthreads();

    long long u = (long long)blockIdx.x * blockDim.x + threadIdx.x;
    if (u >= total_units) return;
    const int e = (int)(u >> 5);
    const int c = (int)(u & 31);
    const int s  = esrc[e];
    const int d  = edst[e];
    const float w = ew[e];

    const float4* xr = (const float4*)(x + (size_t)s * IN_F);
    float acc = 0.f;
    #pragma unroll
    for (int k4 = 0; k4 < IN_F / 4; ++k4) {
        const float4 xv = xr[k4];
        acc += xv.x * Wl[(k4 * 4 + 0) * OUT_F + c];
        acc += xv.y * Wl[(k4 * 4 + 1) * OUT_F + c];
        acc += xv.z * Wl[(k4 * 4 + 2) * OUT_F + c];
        acc += xv.w * Wl[(k4 * 4 + 3) * OUT_F + c];
    }
    atomicAdd(out + (size_t)d * OUT_F + c, w * acc);
}

static inline size_t align_up(size_t v, size_t a) { return (v + a - 1) & ~(a - 1); }

extern "C" void kernel_launch(void* const* d_in, const int* in_sizes, int n_in,
                              void* d_out, int out_size, void* d_ws, size_t ws_size,
                              hipStream_t stream)
{
    const float* x  = (const float*)d_in[0];
    const float* W  = (const float*)d_in[1];
    const int* esrc = (const int*)d_in[2];
    const int* edst = (const int*)d_in[3];
    const float* ew = (const float*)d_in[4];
    float* out = (float*)d_out;

    const int n_nodes = in_sizes[0] / IN_F;
    const int n_edges = in_sizes[2];

    const int nb       = (n_nodes + NPB - 1) >> BSHIFT;    // 391
    const int n_chunks = (n_edges + CHUNK - 1) / CHUNK;    // 391

    const size_t h_bytes    = align_up((size_t)n_nodes * OUT_F * sizeof(unsigned short), 256);
    const size_t cnt_bytes  = align_up((size_t)nb * n_chunks * sizeof(int), 256);
    const size_t off_bytes  = align_up((size_t)nb * n_chunks * sizeof(int), 256);
    const size_t tot_bytes  = align_up((size_t)nb * sizeof(int), 256);
    const size_t col_bytes  = align_up(((size_t)nb + 1) * sizeof(int), 256);
    const size_t recs_bytes = align_up((size_t)n_edges * sizeof(int2) + 16, 256);
    const size_t need = h_bytes + cnt_bytes + off_bytes + tot_bytes + col_bytes + recs_bytes;

    if (ws_size >= need && nb <= MAXB && n_chunks <= 512) {
        char* p = (char*)d_ws;
        unsigned short* h = (unsigned short*)p;  p += h_bytes;
        int* cntT     = (int*)p;                 p += cnt_bytes;
        int* offT     = (int*)p;                 p += off_bytes;
        int* totals   = (int*)p;                 p += tot_bytes;
        int* colStart = (int*)p;                 p += col_bytes;
        int2* recs    = (int2*)p;

        const int gemm_blocks = (n_nodes + 31) / 32;
        gcn_gemm_h<<<gemm_blocks, 256, 0, stream>>>(x, W, h, n_nodes);

        gcn_count<<<n_chunks, BIN_THREADS, 0, stream>>>(edst, cntT, n_edges, nb, n_chunks);
        gcn_scan_bucket<<<nb, 512, 0, stream>>>(cntT, offT, totals, n_chunks, nb);
        gcn_scan_total<<<1, 1024, 0, stream>>>(totals, colStart, nb);
        gcn_bin<<<n_chunks, BIN_THREADS, 0, stream>>>(esrc, edst, ew, colStart, offT,
                                                      recs, n_edges, nb, n_chunks);
        gcn_sort_gather<<<nb, GAT_THREADS, 0, stream>>>(h, recs, colStart, out, n_nodes);
    } else {
        hipMemsetAsync(d_out, 0, (size_t)out_size * sizeof(float), stream);
        const long long total_units = (long long)n_edges * 32;
        const int fblocks = (int)((total_units + 255) / 256);
        gcn_fused_fallback<<<fblocks, 256, 0, stream>>>(x, W, esrc, edst, ew, out, total_units);
    }
}